// Round 1
// baseline (13630.676 us; speedup 1.0000x reference)
//
#include <hip/hip_runtime.h>
#include <hip/hip_bf16.h>

typedef unsigned short u16;
typedef __attribute__((ext_vector_type(8))) short bf16x8;
typedef __attribute__((ext_vector_type(8))) u16   u16x8;
typedef __attribute__((ext_vector_type(4))) float f32x4;

#define T_STEPS 256
#define BATCH   128
#define INDIM   512
#define HDIM    1024
#define GDIM    4096
#define KTOT    1536

#define OFF_XBF   ((size_t)0)
#define XBF_BYTES ((size_t)T_STEPS * BATCH * INDIM * 2)   // 33554432
#define OFF_BM    (OFF_XBF + XBF_BYTES)
#define BM_BYTES  ((size_t)2 * GDIM * KTOT * 2)           // 25165824
#define OFF_HBUF  (OFF_BM + BM_BYTES)
#define HBUF_BYTES ((size_t)2 * 2 * BATCH * HDIM * 2)     // 1048576
#define OFF_BIAS  (OFF_HBUF + HBUF_BYTES)
#define BIAS_BYTES ((size_t)2 * GDIM * 4)                 // 32768
#define OFF_CNT   (OFF_BIAS + BIAS_BYTES)
#define WS_NEED   (OFF_CNT + 256)

__device__ __forceinline__ u16 f2b(float f) {
  __hip_bfloat16 h = __float2bfloat16(f);
  return *reinterpret_cast<u16*>(&h);
}

// ---------------- prepass: cast x to bf16 ----------------
__global__ void k_cast_x(const float* __restrict__ x, u16* __restrict__ xb) {
  size_t i = ((size_t)blockIdx.x * 256 + threadIdx.x) * 8;
  f32x4 a = *reinterpret_cast<const f32x4*>(x + i);
  f32x4 b = *reinterpret_cast<const f32x4*>(x + i + 4);
  u16x8 u;
  u[0] = f2b(a[0]); u[1] = f2b(a[1]); u[2] = f2b(a[2]); u[3] = f2b(a[3]);
  u[4] = f2b(b[0]); u[5] = f2b(b[1]); u[6] = f2b(b[2]); u[7] = f2b(b[3]);
  *reinterpret_cast<u16x8*>(xb + i) = u;
}

// ---------------- prepass: build merged weight matrix ----------------
// Bm[dir][jt 0..63][c 0..63][k 0..1535] bf16, K-contiguous per column.
// column c -> global gate row G = (c>>4)*1024 + jt*16 + (c&15)
// k < 1024 -> Whh[G][k] ; k >= 1024 -> Wih[G][k-1024]
__global__ void k_build_b(const float* __restrict__ Whh_f, const float* __restrict__ Wih_f,
                          const float* __restrict__ Whh_r, const float* __restrict__ Wih_r,
                          u16* __restrict__ Bm) {
  int blk = blockIdx.x;              // 0..127 = dir*64 + jt
  int dir = blk >> 6, jt = blk & 63;
  const float* Whh = dir ? Whh_r : Whh_f;
  const float* Wih = dir ? Wih_r : Wih_f;
  u16* dst = Bm + (size_t)blk * 64 * KTOT;
  for (int c = 0; c < 64; c++) {
    int G = (c >> 4) * HDIM + jt * 16 + (c & 15);
    for (int k = threadIdx.x; k < KTOT; k += 256) {
      float v = (k < HDIM) ? Whh[(size_t)G * HDIM + k] : Wih[(size_t)G * INDIM + (k - HDIM)];
      dst[c * KTOT + k] = f2b(v);
    }
  }
}

// ---------------- prepass: init h buffer, bias, counters ----------------
__global__ void k_init(const float* __restrict__ h0f, const float* __restrict__ h0r,
                       const float* __restrict__ bihf, const float* __restrict__ bhhf,
                       const float* __restrict__ bihr, const float* __restrict__ bhhr,
                       u16* __restrict__ hbuf, float* __restrict__ bias,
                       unsigned* __restrict__ cnt) {
  int i = blockIdx.x * 256 + threadIdx.x;
  if (i < 2 * BATCH * HDIM) {
    int dir = i / (BATCH * HDIM);
    const float* h0 = dir ? h0r : h0f;
    // write h0 into parity buffer 1 (step 0 reads (0+1)&1 = 1)
    hbuf[(size_t)1 * 2 * BATCH * HDIM + i] = f2b(h0[i - dir * BATCH * HDIM]);
  }
  if (i < 2 * GDIM) {
    int dir = i / GDIM, g = i - dir * GDIM;
    bias[i] = dir ? (bihr[g] + bhhr[g]) : (bihf[g] + bhhf[g]);
  }
  if (i < 4) cnt[i] = 0;
}

// ---------------- persistent bidirectional LSTM ----------------
// grid = 256 WGs = dir(2) x mt(2: batch rows 0-63 / 64-127) x jt(64: 16 h-cols each)
// Each WG: GEMM M=64 x N=64(gate cols) x K=1536, 8 waves K-split, weights in regs.
__global__ __launch_bounds__(512, 2) void k_lstm(
    const u16* __restrict__ xb, const u16* __restrict__ Bm,
    u16* __restrict__ hbuf, const float* __restrict__ bias,
    unsigned* __restrict__ cnt,
    const float* __restrict__ c0f, const float* __restrict__ c0r,
    float* __restrict__ out) {
  // LDS: A-tile region (64 rows x 2048B = 131072B, XOR-swizzled),
  // union with partials [w][c 64][68 r] f32 = 139264B
  __shared__ f32x4 lds4[8704];
  char* lds = reinterpret_cast<char*>(lds4);
  float* ldsf = reinterpret_cast<float*>(lds4);

  const int wg  = blockIdx.x;
  const int dir = wg >> 7, mt = (wg >> 6) & 1, jt = wg & 63;
  const int grp = wg >> 6;                     // 0..3
  const int tid = threadIdx.x;
  const int w = tid >> 6, lane = tid & 63;
  const int kk = (lane >> 4) * 8;              // k sub-offset within fragment
  const int ar = lane & 15;

  // ---- load weight fragments into registers (persistent) ----
  const u16* bsrc = Bm + (size_t)(dir * 64 + jt) * 64 * KTOT;
  bf16x8 bh[4][4];  // h-part: wave k-chunk [128w, 128w+128)
  bf16x8 bx[2][4];  // x-part: wave k-chunk [1024+64w, +64)
#pragma unroll
  for (int ks = 0; ks < 4; ks++)
#pragma unroll
    for (int ni = 0; ni < 4; ni++) {
      int c = ni * 16 + ar;
      int k = 128 * w + 32 * ks + kk;
      bh[ks][ni] = *reinterpret_cast<const bf16x8*>(bsrc + (size_t)c * KTOT + k);
    }
#pragma unroll
  for (int ks = 0; ks < 2; ks++)
#pragma unroll
    for (int ni = 0; ni < 4; ni++) {
      int c = ni * 16 + ar;
      int k = HDIM + 64 * w + 32 * ks + kk;
      bx[ks][ni] = *reinterpret_cast<const bf16x8*>(bsrc + (size_t)c * KTOT + k);
    }

  // ---- persistent cell state: thread owns rows {2*r2, 2*r2+1}, col jl ----
  const int r2 = tid >> 4;              // 0..31
  const int jl = tid & 15;              // 0..15
  const int rloc = 2 * r2;              // local row in Mtile
  const int row0 = mt * 64 + rloc;      // global batch row
  const int jglob = jt * 16 + jl;       // global h column
  const float* c0 = dir ? c0r : c0f;
  float cst0 = c0[(size_t)row0 * HDIM + jglob];
  float cst1 = c0[(size_t)(row0 + 1) * HDIM + jglob];
  const float b_i = bias[dir * GDIM + 0 * HDIM + jglob];
  const float b_f = bias[dir * GDIM + 1 * HDIM + jglob];
  const float b_g = bias[dir * GDIM + 2 * HDIM + jglob];
  const float b_o = bias[dir * GDIM + 3 * HDIM + jglob];

  unsigned* mycnt = cnt + grp;

#pragma unroll 1
  for (int s = 0; s < T_STEPS; s++) {
    const int t = dir ? (T_STEPS - 1 - s) : s;

    // ---- phase X: stage x[t] Mtile (64 rows x 512 bf16 = 64KB), swizzled ----
    {
      const char* xsrc = reinterpret_cast<const char*>(
          xb + ((size_t)t * BATCH + mt * 64) * INDIM);
      unsigned off = tid * 16;
#pragma unroll
      for (int i = 0; i < 8; i++) {
        unsigned L = off + i * 8192;
        unsigned r = L >> 10, kb = L & 1023;
        bf16x8 v = *reinterpret_cast<const bf16x8*>(xsrc + L);
        *reinterpret_cast<bf16x8*>(lds + r * 1024 + (kb ^ ((r & 7) << 4))) = v;
      }
    }
    f32x4 acc[4][4];
#pragma unroll
    for (int mi = 0; mi < 4; mi++)
#pragma unroll
      for (int ni = 0; ni < 4; ni++) acc[mi][ni] = f32x4{0.f, 0.f, 0.f, 0.f};
    __syncthreads();

    // ---- x MFMAs (wave k-chunk of 64) ----
#pragma unroll
    for (int ks = 0; ks < 2; ks++)
#pragma unroll
      for (int mi = 0; mi < 4; mi++) {
        unsigned r = 16 * mi + ar;
        unsigned kb = (64 * w + 32 * ks + kk) * 2;
        bf16x8 af = *reinterpret_cast<const bf16x8*>(lds + r * 1024 + (kb ^ ((r & 7) << 4)));
#pragma unroll
        for (int ni = 0; ni < 4; ni++)
          acc[mi][ni] = __builtin_amdgcn_mfma_f32_16x16x32_bf16(af, bx[ks][ni], acc[mi][ni], 0, 0, 0);
      }

    // ---- wait for h_{s-1} from our group's 64 WGs ----
    if (tid == 0 && s > 0) {
      unsigned target = (unsigned)(64 * s);
      while (__hip_atomic_load(mycnt, __ATOMIC_ACQUIRE, __HIP_MEMORY_SCOPE_AGENT) < target)
        __builtin_amdgcn_s_sleep(2);
    }
    __syncthreads();
    if (s > 0) __threadfence();   // acquire: invalidate so h loads are fresh

    // ---- phase H: stage h_{t-1} Mtile (64 rows x 1024 bf16 = 128KB), swizzled ----
    {
      const char* hsrc = reinterpret_cast<const char*>(
          hbuf + (((size_t)((s + 1) & 1) * 2 + dir) * BATCH + (size_t)mt * 64) * HDIM);
      unsigned off = tid * 16;
#pragma unroll
      for (int i = 0; i < 16; i++) {
        unsigned L = off + i * 8192;
        unsigned r = L >> 11, kb = L & 2047;
        bf16x8 v = *reinterpret_cast<const bf16x8*>(hsrc + L);
        *reinterpret_cast<bf16x8*>(lds + r * 2048 + (kb ^ ((r & 7) << 4))) = v;
      }
    }
    __syncthreads();

    // ---- h MFMAs (wave k-chunk of 128) ----
#pragma unroll
    for (int ks = 0; ks < 4; ks++)
#pragma unroll
      for (int mi = 0; mi < 4; mi++) {
        unsigned r = 16 * mi + ar;
        unsigned kb = (128 * w + 32 * ks + kk) * 2;
        bf16x8 af = *reinterpret_cast<const bf16x8*>(lds + r * 2048 + (kb ^ ((r & 7) << 4)));
#pragma unroll
        for (int ni = 0; ni < 4; ni++)
          acc[mi][ni] = __builtin_amdgcn_mfma_f32_16x16x32_bf16(af, bh[ks][ni], acc[mi][ni], 0, 0, 0);
      }
    __syncthreads();   // A-tile dead; partials may overwrite

    // ---- write per-wave partials: [w][c 64][68 r] f32, col-major ----
    {
      float* pw = ldsf + w * (64 * 68);
#pragma unroll
      for (int mi = 0; mi < 4; mi++)
#pragma unroll
        for (int ni = 0; ni < 4; ni++) {
          int c = ni * 16 + ar;
          int r = mi * 16 + (lane >> 4) * 4;
          *reinterpret_cast<f32x4*>(pw + c * 68 + r) = acc[mi][ni];
        }
    }
    __syncthreads();

    // ---- reduce 8 partials + gating (thread: 2 rows, 1 col) ----
    {
      float gi0 = b_i, gi1 = b_i, gf0 = b_f, gf1 = b_f;
      float gg0 = b_g, gg1 = b_g, go0 = b_o, go1 = b_o;
#pragma unroll
      for (int ww = 0; ww < 8; ww++) {
        const float* p = ldsf + ww * (64 * 68);
        float2 vi = *reinterpret_cast<const float2*>(p + (0 * 16 + jl) * 68 + rloc);
        float2 vf = *reinterpret_cast<const float2*>(p + (1 * 16 + jl) * 68 + rloc);
        float2 vg = *reinterpret_cast<const float2*>(p + (2 * 16 + jl) * 68 + rloc);
        float2 vo = *reinterpret_cast<const float2*>(p + (3 * 16 + jl) * 68 + rloc);
        gi0 += vi.x; gi1 += vi.y; gf0 += vf.x; gf1 += vf.y;
        gg0 += vg.x; gg1 += vg.y; go0 += vo.x; go1 += vo.y;
      }
      float i0 = 1.f / (1.f + __expf(-gi0)), i1 = 1.f / (1.f + __expf(-gi1));
      float f0 = 1.f / (1.f + __expf(-gf0)), f1 = 1.f / (1.f + __expf(-gf1));
      float g0 = tanhf(gg0), g1 = tanhf(gg1);
      float o0 = 1.f / (1.f + __expf(-go0)), o1 = 1.f / (1.f + __expf(-go1));
      cst0 = f0 * cst0 + i0 * g0;
      cst1 = f1 * cst1 + i1 * g1;
      float h0v = o0 * tanhf(cst0);
      float h1v = o1 * tanhf(cst1);

      // y output [t][row][dir*H + j]
      size_t ybase = ((size_t)t * BATCH + row0) * (2 * HDIM) + (size_t)dir * HDIM + jglob;
      out[ybase] = h0v;
      out[ybase + 2 * HDIM] = h1v;

      // broadcast h (bf16) for next step
      u16* hdst = hbuf + ((size_t)(s & 1) * 2 + dir) * BATCH * HDIM;
      hdst[(size_t)row0 * HDIM + jglob] = f2b(h0v);
      hdst[(size_t)(row0 + 1) * HDIM + jglob] = f2b(h1v);

      if (s == T_STEPS - 1) {
        // hidden = [hf; cf] then cell = [hr; cr], after y block
        size_t hid = (size_t)T_STEPS * BATCH * 2 * HDIM;
        size_t base2 = hid + (size_t)dir * 2 * BATCH * HDIM;
        out[base2 + (size_t)row0 * HDIM + jglob] = h0v;
        out[base2 + (size_t)(row0 + 1) * HDIM + jglob] = h1v;
        out[base2 + (size_t)BATCH * HDIM + (size_t)row0 * HDIM + jglob] = cst0;
        out[base2 + (size_t)BATCH * HDIM + (size_t)(row0 + 1) * HDIM + jglob] = cst1;
      }
    }

    // ---- arrive: release h to the group ----
    __syncthreads();
    if (tid == 0) {
      __threadfence();
      __hip_atomic_fetch_add(mycnt, 1u, __ATOMIC_RELEASE, __HIP_MEMORY_SCOPE_AGENT);
    }
  }
}

extern "C" void kernel_launch(void* const* d_in, const int* in_sizes, int n_in,
                              void* d_out, int out_size, void* d_ws, size_t ws_size,
                              hipStream_t stream) {
  const float* x     = (const float*)d_in[0];
  const float* h0f   = (const float*)d_in[1];
  const float* c0f   = (const float*)d_in[2];
  const float* h0r   = (const float*)d_in[3];
  const float* c0r   = (const float*)d_in[4];
  const float* Wih_f = (const float*)d_in[5];
  const float* Whh_f = (const float*)d_in[6];
  const float* bih_f = (const float*)d_in[7];
  const float* bhh_f = (const float*)d_in[8];
  const float* Wih_r = (const float*)d_in[9];
  const float* Whh_r = (const float*)d_in[10];
  const float* bih_r = (const float*)d_in[11];
  const float* bhh_r = (const float*)d_in[12];
  float* out = (float*)d_out;
  char* ws = (char*)d_ws;

  if (ws_size < WS_NEED) return;  // visible (absmax) failure rather than OOB crash

  u16* xbf      = (u16*)(ws + OFF_XBF);
  u16* Bm       = (u16*)(ws + OFF_BM);
  u16* hbuf     = (u16*)(ws + OFF_HBUF);
  float* bias   = (float*)(ws + OFF_BIAS);
  unsigned* cnt = (unsigned*)(ws + OFF_CNT);

  k_cast_x<<<8192, 256, 0, stream>>>(x, xbf);
  k_build_b<<<128, 256, 0, stream>>>(Whh_f, Wih_f, Whh_r, Wih_r, Bm);
  k_init<<<1024, 256, 0, stream>>>(h0f, h0r, bih_f, bhh_f, bih_r, bhh_r, hbuf, bias, cnt);
  k_lstm<<<256, 512, 0, stream>>>(xbf, Bm, hbuf, bias, cnt, c0f, c0r, out);
}

// Round 2
// 3150.163 us; speedup vs baseline: 4.3270x; 4.3270x over previous
//
#include <hip/hip_runtime.h>
#include <hip/hip_bf16.h>

typedef unsigned short u16;
typedef __attribute__((ext_vector_type(8))) short bf16x8;
typedef __attribute__((ext_vector_type(8))) u16   u16x8;
typedef __attribute__((ext_vector_type(4))) float f32x4;

#define T_STEPS 256
#define BATCH   128
#define INDIM   512
#define HDIM    1024
#define GDIM    4096
#define KTOT    1536

#define OFF_XBF   ((size_t)0)
#define XBF_BYTES ((size_t)T_STEPS * BATCH * INDIM * 2)   // 33554432
#define OFF_BM    (OFF_XBF + XBF_BYTES)
#define BM_BYTES  ((size_t)2 * GDIM * KTOT * 2)           // 25165824
#define OFF_HBUF  (OFF_BM + BM_BYTES)
#define HBUF_BYTES ((size_t)2 * 2 * BATCH * HDIM * 2)     // 1048576
#define OFF_BIAS  (OFF_HBUF + HBUF_BYTES)
#define BIAS_BYTES ((size_t)2 * GDIM * 4)                 // 32768
#define OFF_CNT   (OFF_BIAS + BIAS_BYTES)
#define WS_NEED   (OFF_CNT + 1024)

__device__ __forceinline__ u16 f2b(float f) {
  __hip_bfloat16 h = __float2bfloat16(f);
  return *reinterpret_cast<u16*>(&h);
}

union U8 { unsigned long long q[2]; bf16x8 v; };

// ---------------- prepass: cast x to bf16 ----------------
__global__ void k_cast_x(const float* __restrict__ x, u16* __restrict__ xb) {
  size_t i = ((size_t)blockIdx.x * 256 + threadIdx.x) * 8;
  f32x4 a = *reinterpret_cast<const f32x4*>(x + i);
  f32x4 b = *reinterpret_cast<const f32x4*>(x + i + 4);
  u16x8 u;
  u[0] = f2b(a[0]); u[1] = f2b(a[1]); u[2] = f2b(a[2]); u[3] = f2b(a[3]);
  u[4] = f2b(b[0]); u[5] = f2b(b[1]); u[6] = f2b(b[2]); u[7] = f2b(b[3]);
  *reinterpret_cast<u16x8*>(xb + i) = u;
}

// ---------------- prepass: build merged weight matrix ----------------
// Bm[dir][jt 0..63][c 0..63][k 0..1535] bf16, K-contiguous per column.
// column c -> global gate row G = (c>>4)*1024 + jt*16 + (c&15)
// k < 1024 -> Whh[G][k] ; k >= 1024 -> Wih[G][k-1024]
__global__ void k_build_b(const float* __restrict__ Whh_f, const float* __restrict__ Wih_f,
                          const float* __restrict__ Whh_r, const float* __restrict__ Wih_r,
                          u16* __restrict__ Bm) {
  int blk = blockIdx.x;              // 0..127 = dir*64 + jt
  int dir = blk >> 6, jt = blk & 63;
  const float* Whh = dir ? Whh_r : Whh_f;
  const float* Wih = dir ? Wih_r : Wih_f;
  u16* dst = Bm + (size_t)blk * 64 * KTOT;
  for (int c = 0; c < 64; c++) {
    int G = (c >> 4) * HDIM + jt * 16 + (c & 15);
    for (int k = threadIdx.x; k < KTOT; k += 256) {
      float v = (k < HDIM) ? Whh[(size_t)G * HDIM + k] : Wih[(size_t)G * INDIM + (k - HDIM)];
      dst[c * KTOT + k] = f2b(v);
    }
  }
}

// ---------------- prepass: init h buffer, bias, flags ----------------
__global__ void k_init(const float* __restrict__ h0f, const float* __restrict__ h0r,
                       const float* __restrict__ bihf, const float* __restrict__ bhhf,
                       const float* __restrict__ bihr, const float* __restrict__ bhhr,
                       u16* __restrict__ hbuf, float* __restrict__ bias,
                       unsigned* __restrict__ flags) {
  int i = blockIdx.x * 256 + threadIdx.x;
  if (i < 2 * BATCH * HDIM) {
    int dir = i / (BATCH * HDIM);
    const float* h0 = dir ? h0r : h0f;
    // write h0 into parity buffer 1 (step 0 reads (0+1)&1 = 1)
    hbuf[(size_t)1 * 2 * BATCH * HDIM + i] = f2b(h0[i - dir * BATCH * HDIM]);
  }
  if (i < 2 * GDIM) {
    int dir = i / GDIM, g = i - dir * GDIM;
    bias[i] = dir ? (bihr[g] + bhhr[g]) : (bihf[g] + bhhf[g]);
  }
  if (i < 256) flags[i] = 0;
}

// ---------------- persistent bidirectional LSTM ----------------
// grid = 256 WGs = dir(2) x mt(2: batch rows 0-63/64-127) x jt(64: 16 h-cols)
// Per WG: GEMM M=64 x N=64(gate cols) x K=1536, 8 waves K-split, B in regs,
// A-fragments loaded direct global->VGPR (h via LLC-coherent sc1 loads).
__global__ __launch_bounds__(512, 2) void k_lstm(
    const u16* __restrict__ xb, const u16* __restrict__ Bm,
    u16* __restrict__ hbuf, const float* __restrict__ bias,
    unsigned* __restrict__ flags,
    const float* __restrict__ c0f, const float* __restrict__ c0r,
    float* __restrict__ out) {
  __shared__ float ldsf[8 * 64 * 68];   // 139264 B partials only

  const int wg  = blockIdx.x;
  const int dir = wg >> 7, mt = (wg >> 6) & 1, jt = wg & 63;
  const int grp = wg >> 6;                     // 0..3
  const int tid = threadIdx.x;
  const int w = tid >> 6, lane = tid & 63;
  const int kk = (lane >> 4) * 8;
  const int ar = lane & 15;

  // ---- persistent h-part weight fragments in registers ----
  const u16* bsrc = Bm + (size_t)(dir * 64 + jt) * 64 * KTOT;
  bf16x8 bh[4][4];
#pragma unroll
  for (int ks = 0; ks < 4; ks++)
#pragma unroll
    for (int ni = 0; ni < 4; ni++)
      bh[ks][ni] = *reinterpret_cast<const bf16x8*>(
          bsrc + (size_t)(ni * 16 + ar) * KTOT + 128 * w + 32 * ks + kk);

  // ---- gating thread mapping: 1 row x 2 adjacent cols per thread ----
  const int rrow = tid >> 3;            // 0..63 local row
  const int cp   = tid & 7;             // col pair 0..7
  const int jl0  = 2 * cp;
  const int row0 = mt * 64 + rrow;      // global batch row
  const int jg0  = jt * 16 + jl0;       // global h column (even)
  const float* c0 = dir ? c0r : c0f;
  float2 cc = *reinterpret_cast<const float2*>(c0 + (size_t)row0 * HDIM + jg0);
  float cst0 = cc.x, cst1 = cc.y;
  const float2 b_i = *reinterpret_cast<const float2*>(bias + dir * GDIM + 0 * HDIM + jg0);
  const float2 b_f = *reinterpret_cast<const float2*>(bias + dir * GDIM + 1 * HDIM + jg0);
  const float2 b_g = *reinterpret_cast<const float2*>(bias + dir * GDIM + 2 * HDIM + jg0);
  const float2 b_o = *reinterpret_cast<const float2*>(bias + dir * GDIM + 3 * HDIM + jg0);

#pragma unroll 1
  for (int s = 0; s < T_STEPS; s++) {
    const int t = dir ? (T_STEPS - 1 - s) : s;

    f32x4 acc[4][4];
#pragma unroll
    for (int mi = 0; mi < 4; mi++)
#pragma unroll
      for (int ni = 0; ni < 4; ni++) acc[mi][ni] = f32x4{0.f, 0.f, 0.f, 0.f};

    // ---- x phase: direct-frag loads (plain) + MFMA, before the wait ----
    {
      const u16* xsrc = xb + ((size_t)t * BATCH + mt * 64) * INDIM;
#pragma unroll
      for (int ks = 0; ks < 2; ks++) {
        bf16x8 axm[4], bxn[4];
#pragma unroll
        for (int mi = 0; mi < 4; mi++)
          axm[mi] = *reinterpret_cast<const bf16x8*>(
              xsrc + (size_t)(16 * mi + ar) * INDIM + 64 * w + 32 * ks + kk);
#pragma unroll
        for (int ni = 0; ni < 4; ni++)
          bxn[ni] = *reinterpret_cast<const bf16x8*>(
              bsrc + (size_t)(ni * 16 + ar) * KTOT + HDIM + 64 * w + 32 * ks + kk);
#pragma unroll
        for (int mi = 0; mi < 4; mi++)
#pragma unroll
          for (int ni = 0; ni < 4; ni++)
            acc[mi][ni] = __builtin_amdgcn_mfma_f32_16x16x32_bf16(axm[mi], bxn[ni], acc[mi][ni], 0, 0, 0);
      }
    }

    // ---- wait for h_{s-1}: wave 0 polls 64 per-producer flags ----
    if (s > 0) {
      if (w == 0) {
        const unsigned* fp = flags + grp * 64 + lane;
        while (true) {
          unsigned f = __hip_atomic_load(fp, __ATOMIC_RELAXED, __HIP_MEMORY_SCOPE_AGENT);
          if (__all((int)(f >= (unsigned)s))) break;
          __builtin_amdgcn_s_sleep(1);
        }
      }
      __syncthreads();
    }

    // ---- h phase: direct-frag LLC-coherent loads + MFMA ----
    {
      const u16* hbase = hbuf + ((size_t)((s + 1) & 1) * 2 + dir) * BATCH * HDIM
                              + (size_t)mt * 64 * HDIM;
      bf16x8 ah[4][4];
#pragma unroll
      for (int ks = 0; ks < 4; ks++)
#pragma unroll
        for (int mi = 0; mi < 4; mi++) {
          const unsigned long long* p = reinterpret_cast<const unsigned long long*>(
              hbase + (size_t)(16 * mi + ar) * HDIM + 128 * w + 32 * ks + kk);
          unsigned long long lo = __hip_atomic_load(p,     __ATOMIC_RELAXED, __HIP_MEMORY_SCOPE_AGENT);
          unsigned long long hi = __hip_atomic_load(p + 1, __ATOMIC_RELAXED, __HIP_MEMORY_SCOPE_AGENT);
          U8 u; u.q[0] = lo; u.q[1] = hi;
          ah[ks][mi] = u.v;
        }
#pragma unroll
      for (int ks = 0; ks < 4; ks++)
#pragma unroll
        for (int mi = 0; mi < 4; mi++)
#pragma unroll
          for (int ni = 0; ni < 4; ni++)
            acc[mi][ni] = __builtin_amdgcn_mfma_f32_16x16x32_bf16(ah[ks][mi], bh[ks][ni], acc[mi][ni], 0, 0, 0);
    }

    // ---- write per-wave partials: [w][c 64][68 r] f32, col-major ----
    {
      float* pw = ldsf + w * (64 * 68);
#pragma unroll
      for (int mi = 0; mi < 4; mi++)
#pragma unroll
        for (int ni = 0; ni < 4; ni++)
          *reinterpret_cast<f32x4*>(pw + (ni * 16 + ar) * 68 + mi * 16 + (lane >> 4) * 4) = acc[mi][ni];
    }
    __syncthreads();

    // ---- reduce 8 partials + gating (thread: 1 row, 2 cols) ----
    {
      float gi0 = b_i.x, gi1 = b_i.y, gf0 = b_f.x, gf1 = b_f.y;
      float gg0 = b_g.x, gg1 = b_g.y, go0 = b_o.x, go1 = b_o.y;
#pragma unroll
      for (int ww = 0; ww < 8; ww++) {
        const float* p = ldsf + ww * (64 * 68);
        gi0 += p[(0 * 16 + jl0) * 68 + rrow]; gi1 += p[(0 * 16 + jl0 + 1) * 68 + rrow];
        gf0 += p[(1 * 16 + jl0) * 68 + rrow]; gf1 += p[(1 * 16 + jl0 + 1) * 68 + rrow];
        gg0 += p[(2 * 16 + jl0) * 68 + rrow]; gg1 += p[(2 * 16 + jl0 + 1) * 68 + rrow];
        go0 += p[(3 * 16 + jl0) * 68 + rrow]; go1 += p[(3 * 16 + jl0 + 1) * 68 + rrow];
      }
      float i0 = 1.f / (1.f + __expf(-gi0)), i1 = 1.f / (1.f + __expf(-gi1));
      float f0 = 1.f / (1.f + __expf(-gf0)), f1 = 1.f / (1.f + __expf(-gf1));
      float g0 = tanhf(gg0), g1 = tanhf(gg1);
      float o0 = 1.f / (1.f + __expf(-go0)), o1 = 1.f / (1.f + __expf(-go1));
      cst0 = f0 * cst0 + i0 * g0;
      cst1 = f1 * cst1 + i1 * g1;
      float h0v = o0 * tanhf(cst0);
      float h1v = o1 * tanhf(cst1);

      float2 yv; yv.x = h0v; yv.y = h1v;
      *reinterpret_cast<float2*>(out + ((size_t)t * BATCH + row0) * (2 * HDIM)
                                     + (size_t)dir * HDIM + jg0) = yv;

      // broadcast h (packed 2x bf16, LLC write-through) for next step
      u16* hdst = hbuf + ((size_t)(s & 1) * 2 + dir) * BATCH * HDIM;
      unsigned hp = (unsigned)f2b(h0v) | ((unsigned)f2b(h1v) << 16);
      __hip_atomic_store(reinterpret_cast<unsigned*>(hdst + (size_t)row0 * HDIM + jg0),
                         hp, __ATOMIC_RELAXED, __HIP_MEMORY_SCOPE_AGENT);

      if (s == T_STEPS - 1) {
        size_t hid = (size_t)T_STEPS * BATCH * 2 * HDIM;
        size_t base2 = hid + (size_t)dir * 2 * BATCH * HDIM;
        *reinterpret_cast<float2*>(out + base2 + (size_t)row0 * HDIM + jg0) = yv;
        float2 cv; cv.x = cst0; cv.y = cst1;
        *reinterpret_cast<float2*>(out + base2 + (size_t)BATCH * HDIM
                                       + (size_t)row0 * HDIM + jg0) = cv;
      }
    }

    // ---- manual release: ack own stores -> all waves done -> post flag ----
    asm volatile("s_waitcnt vmcnt(0)" ::: "memory");
    __syncthreads();
    if (tid == 0)
      __hip_atomic_store(flags + grp * 64 + jt, (unsigned)(s + 1),
                         __ATOMIC_RELAXED, __HIP_MEMORY_SCOPE_AGENT);
  }
}

extern "C" void kernel_launch(void* const* d_in, const int* in_sizes, int n_in,
                              void* d_out, int out_size, void* d_ws, size_t ws_size,
                              hipStream_t stream) {
  const float* x     = (const float*)d_in[0];
  const float* h0f   = (const float*)d_in[1];
  const float* c0f   = (const float*)d_in[2];
  const float* h0r   = (const float*)d_in[3];
  const float* c0r   = (const float*)d_in[4];
  const float* Wih_f = (const float*)d_in[5];
  const float* Whh_f = (const float*)d_in[6];
  const float* bih_f = (const float*)d_in[7];
  const float* bhh_f = (const float*)d_in[8];
  const float* Wih_r = (const float*)d_in[9];
  const float* Whh_r = (const float*)d_in[10];
  const float* bih_r = (const float*)d_in[11];
  const float* bhh_r = (const float*)d_in[12];
  float* out = (float*)d_out;
  char* ws = (char*)d_ws;

  if (ws_size < WS_NEED) return;

  u16* xbf        = (u16*)(ws + OFF_XBF);
  u16* Bm         = (u16*)(ws + OFF_BM);
  u16* hbuf       = (u16*)(ws + OFF_HBUF);
  float* bias     = (float*)(ws + OFF_BIAS);
  unsigned* flags = (unsigned*)(ws + OFF_CNT);

  k_cast_x<<<8192, 256, 0, stream>>>(x, xbf);
  k_build_b<<<128, 256, 0, stream>>>(Whh_f, Wih_f, Whh_r, Wih_r, Bm);
  k_init<<<1024, 256, 0, stream>>>(h0f, h0r, bih_f, bhh_f, bih_r, bhh_r, hbuf, bias, flags);
  k_lstm<<<256, 512, 0, stream>>>(xbf, Bm, hbuf, bias, flags, c0f, c0r, out);
}

// Round 3
// 2628.599 us; speedup vs baseline: 5.1855x; 1.1984x over previous
//
#include <hip/hip_runtime.h>
#include <hip/hip_bf16.h>

typedef unsigned short u16;
typedef __attribute__((ext_vector_type(8))) short bf16x8;
typedef __attribute__((ext_vector_type(8))) u16   u16x8;
typedef __attribute__((ext_vector_type(4))) float f32x4;

#define T_STEPS 256
#define BATCH   128
#define INDIM   512
#define HDIM    1024
#define GDIM    4096
#define KTOT    1536

#define OFF_XBF   ((size_t)0)
#define XBF_BYTES ((size_t)T_STEPS * BATCH * INDIM * 2)   // 33554432
#define OFF_BM    (OFF_XBF + XBF_BYTES)
#define BM_BYTES  ((size_t)2 * GDIM * KTOT * 2)           // 25165824
#define OFF_HBUF  (OFF_BM + BM_BYTES)
#define HBUF_BYTES ((size_t)2 * 2 * BATCH * HDIM * 2)     // 1048576 (fallback parity buf)
#define OFF_BIAS  (OFF_HBUF + HBUF_BYTES)
#define BIAS_BYTES ((size_t)2 * GDIM * 4)                 // 32768
#define OFF_CNT   (OFF_BIAS + BIAS_BYTES)
#define OFF_ROLL  (OFF_CNT + 1024)
#define ROLL_BYTES ((size_t)(T_STEPS + 1) * 2 * BATCH * HDIM * 2)  // 134742016
#define WS_SMALL  OFF_ROLL
#define WS_BIG    (OFF_ROLL + ROLL_BYTES)

__device__ __forceinline__ u16 f2b(float f) {
  __hip_bfloat16 h = __float2bfloat16(f);
  return *reinterpret_cast<u16*>(&h);
}

union U8 { unsigned long long q[2]; bf16x8 v; };

// ---------------- prepass: cast x to bf16 ----------------
__global__ void k_cast_x(const float* __restrict__ x, u16* __restrict__ xb) {
  size_t i = ((size_t)blockIdx.x * 256 + threadIdx.x) * 8;
  f32x4 a = *reinterpret_cast<const f32x4*>(x + i);
  f32x4 b = *reinterpret_cast<const f32x4*>(x + i + 4);
  u16x8 u;
  u[0] = f2b(a[0]); u[1] = f2b(a[1]); u[2] = f2b(a[2]); u[3] = f2b(a[3]);
  u[4] = f2b(b[0]); u[5] = f2b(b[1]); u[6] = f2b(b[2]); u[7] = f2b(b[3]);
  *reinterpret_cast<u16x8*>(xb + i) = u;
}

// ---------------- prepass: build merged weight matrix ----------------
// Bm[dir][jt][c 0..63][k 0..1535] bf16; col c -> gate row G=(c>>4)*1024+jt*16+(c&15)
__global__ void k_build_b(const float* __restrict__ Whh_f, const float* __restrict__ Wih_f,
                          const float* __restrict__ Whh_r, const float* __restrict__ Wih_r,
                          u16* __restrict__ Bm) {
  int blk = blockIdx.x;              // 0..127 = dir*64 + jt
  int dir = blk >> 6, jt = blk & 63;
  const float* Whh = dir ? Whh_r : Whh_f;
  const float* Wih = dir ? Wih_r : Wih_f;
  u16* dst = Bm + (size_t)blk * 64 * KTOT;
  for (int c = 0; c < 64; c++) {
    int G = (c >> 6) * 0 + (c >> 4) * HDIM + jt * 16 + (c & 15);
    for (int k = threadIdx.x; k < KTOT; k += 256) {
      float v = (k < HDIM) ? Whh[(size_t)G * HDIM + k] : Wih[(size_t)G * INDIM + (k - HDIM)];
      dst[c * KTOT + k] = f2b(v);
    }
  }
}

// ---------------- prepass: init h buffers, bias, flags ----------------
__global__ void k_init(const float* __restrict__ h0f, const float* __restrict__ h0r,
                       const float* __restrict__ bihf, const float* __restrict__ bhhf,
                       const float* __restrict__ bihr, const float* __restrict__ bhhr,
                       u16* __restrict__ hbuf, u16* __restrict__ hroll, int use_roll,
                       float* __restrict__ bias, unsigned* __restrict__ flags) {
  int i = blockIdx.x * 256 + threadIdx.x;
  if (i < 2 * BATCH * HDIM) {
    int dir = i / (BATCH * HDIM);
    const float* h0 = dir ? h0r : h0f;
    u16 hv = f2b(h0[i - dir * BATCH * HDIM]);
    // fallback parity buffer: step 0 reads parity (0+1)&1 = 1
    hbuf[(size_t)1 * 2 * BATCH * HDIM + i] = hv;
    if (use_roll) hroll[i] = hv;   // roll slot 0
  }
  if (i < 2 * GDIM) {
    int dir = i / GDIM, g = i - dir * GDIM;
    bias[i] = dir ? (bihr[g] + bhhr[g]) : (bihf[g] + bhhf[g]);
  }
  if (i < 256) flags[i] = 0;
}

// ---------------- persistent bidirectional LSTM ----------------
// grid = 256 WGs = dir(2) x mt(2) x jt(64); per WG GEMM M=64 x N=64 x K=1536,
// 8 waves K-split, B weights in regs, h from step-indexed roll buffer (L2-cached).
__global__ __launch_bounds__(512, 2) void k_lstm(
    const u16* __restrict__ xb, const u16* __restrict__ Bm,
    u16* __restrict__ hbuf, u16* __restrict__ hroll, int use_roll,
    const float* __restrict__ bias, unsigned* __restrict__ flags,
    const float* __restrict__ c0f, const float* __restrict__ c0r,
    float* __restrict__ out) {
  __shared__ float ldsf[8 * 64 * 68];   // 139264 B partials

  // Purge any stale L2 lines from a previous graph replay (roll addresses are
  // reused across replays). Once per WG, before any global load.
  __builtin_amdgcn_fence(__ATOMIC_ACQUIRE, "agent");

  const int wg  = blockIdx.x;
  const int dir = wg >> 7, mt = (wg >> 6) & 1, jt = wg & 63;
  const int grp = wg >> 6;                     // 0..3
  const int tid = threadIdx.x;
  const int w = tid >> 6, lane = tid & 63;
  const int kk = (lane >> 4) * 8;
  const int ar = lane & 15;

  // ---- persistent h-part weight fragments in registers ----
  const u16* bsrc = Bm + (size_t)(dir * 64 + jt) * 64 * KTOT;
  bf16x8 bh[4][4];
#pragma unroll
  for (int ks = 0; ks < 4; ks++)
#pragma unroll
    for (int ni = 0; ni < 4; ni++)
      bh[ks][ni] = *reinterpret_cast<const bf16x8*>(
          bsrc + (size_t)(ni * 16 + ar) * KTOT + 128 * w + 32 * ks + kk);

  // ---- gating thread mapping: 1 row x 2 adjacent cols per thread ----
  const int rrow = tid >> 3;            // 0..63 local row
  const int cp   = tid & 7;             // col pair 0..7
  const int jl0  = 2 * cp;
  const int row0 = mt * 64 + rrow;      // global batch row
  const int jg0  = jt * 16 + jl0;       // global h column (even)
  const float* c0 = dir ? c0r : c0f;
  float2 cc = *reinterpret_cast<const float2*>(c0 + (size_t)row0 * HDIM + jg0);
  float cst0 = cc.x, cst1 = cc.y;
  const float2 b_i = *reinterpret_cast<const float2*>(bias + dir * GDIM + 0 * HDIM + jg0);
  const float2 b_f = *reinterpret_cast<const float2*>(bias + dir * GDIM + 1 * HDIM + jg0);
  const float2 b_g = *reinterpret_cast<const float2*>(bias + dir * GDIM + 2 * HDIM + jg0);
  const float2 b_o = *reinterpret_cast<const float2*>(bias + dir * GDIM + 3 * HDIM + jg0);

#pragma unroll 1
  for (int s = 0; s < T_STEPS; s++) {
    const int t = dir ? (T_STEPS - 1 - s) : s;

    f32x4 acc[4][4];
#pragma unroll
    for (int mi = 0; mi < 4; mi++)
#pragma unroll
      for (int ni = 0; ni < 4; ni++) acc[mi][ni] = f32x4{0.f, 0.f, 0.f, 0.f};

    // ---- x phase: direct-frag loads (cached) + MFMA, before the wait ----
    {
      const u16* xsrc = xb + ((size_t)t * BATCH + mt * 64) * INDIM;
#pragma unroll
      for (int ks = 0; ks < 2; ks++) {
        bf16x8 axm[4], bxn[4];
#pragma unroll
        for (int mi = 0; mi < 4; mi++)
          axm[mi] = *reinterpret_cast<const bf16x8*>(
              xsrc + (size_t)(16 * mi + ar) * INDIM + 64 * w + 32 * ks + kk);
#pragma unroll
        for (int ni = 0; ni < 4; ni++)
          bxn[ni] = *reinterpret_cast<const bf16x8*>(
              bsrc + (size_t)(ni * 16 + ar) * KTOT + HDIM + 64 * w + 32 * ks + kk);
#pragma unroll
        for (int mi = 0; mi < 4; mi++)
#pragma unroll
          for (int ni = 0; ni < 4; ni++)
            acc[mi][ni] = __builtin_amdgcn_mfma_f32_16x16x32_bf16(axm[mi], bxn[ni], acc[mi][ni], 0, 0, 0);
      }
    }

    // ---- wait for h_{s-1}: wave 0 polls 64 per-producer flags ----
    if (s > 0) {
      if (w == 0) {
        const unsigned* fp = flags + grp * 64 + lane;
        while (true) {
          unsigned f = __hip_atomic_load(fp, __ATOMIC_RELAXED, __HIP_MEMORY_SCOPE_AGENT);
          if (__all((int)(f >= (unsigned)s))) break;
          __builtin_amdgcn_s_sleep(1);
        }
      }
      __syncthreads();
    }

    // ---- h phase ----
    {
      bf16x8 ah[4][4];
      if (use_roll) {
        // plain cached loads from step-slot s (written exactly once, fresh)
        const u16* hRd = hroll + ((size_t)s * 2 + dir) * BATCH * HDIM
                               + (size_t)mt * 64 * HDIM;
#pragma unroll
        for (int ks = 0; ks < 4; ks++)
#pragma unroll
          for (int mi = 0; mi < 4; mi++)
            ah[ks][mi] = *reinterpret_cast<const bf16x8*>(
                hRd + (size_t)(16 * mi + ar) * HDIM + 128 * w + 32 * ks + kk);
      } else {
        // fallback: LLC-coherent loads from parity buffer
        const u16* hbase = hbuf + ((size_t)((s + 1) & 1) * 2 + dir) * BATCH * HDIM
                                + (size_t)mt * 64 * HDIM;
#pragma unroll
        for (int ks = 0; ks < 4; ks++)
#pragma unroll
          for (int mi = 0; mi < 4; mi++) {
            const unsigned long long* p = reinterpret_cast<const unsigned long long*>(
                hbase + (size_t)(16 * mi + ar) * HDIM + 128 * w + 32 * ks + kk);
            unsigned long long lo = __hip_atomic_load(p,     __ATOMIC_RELAXED, __HIP_MEMORY_SCOPE_AGENT);
            unsigned long long hi = __hip_atomic_load(p + 1, __ATOMIC_RELAXED, __HIP_MEMORY_SCOPE_AGENT);
            U8 u; u.q[0] = lo; u.q[1] = hi;
            ah[ks][mi] = u.v;
          }
      }
#pragma unroll
      for (int ks = 0; ks < 4; ks++)
#pragma unroll
        for (int mi = 0; mi < 4; mi++)
#pragma unroll
          for (int ni = 0; ni < 4; ni++)
            acc[mi][ni] = __builtin_amdgcn_mfma_f32_16x16x32_bf16(ah[ks][mi], bh[ks][ni], acc[mi][ni], 0, 0, 0);
    }

    // ---- write per-wave partials: [w][c 64][68 r] f32, col-major ----
    {
      float* pw = ldsf + w * (64 * 68);
#pragma unroll
      for (int mi = 0; mi < 4; mi++)
#pragma unroll
        for (int ni = 0; ni < 4; ni++)
          *reinterpret_cast<f32x4*>(pw + (ni * 16 + ar) * 68 + mi * 16 + (lane >> 4) * 4) = acc[mi][ni];
    }
    __syncthreads();

    // ---- reduce 8 partials + gating (thread: 1 row, 2 cols) ----
    {
      float gi0 = b_i.x, gi1 = b_i.y, gf0 = b_f.x, gf1 = b_f.y;
      float gg0 = b_g.x, gg1 = b_g.y, go0 = b_o.x, go1 = b_o.y;
#pragma unroll
      for (int ww = 0; ww < 8; ww++) {
        const float* p = ldsf + ww * (64 * 68);
        gi0 += p[(0 * 16 + jl0) * 68 + rrow]; gi1 += p[(0 * 16 + jl0 + 1) * 68 + rrow];
        gf0 += p[(1 * 16 + jl0) * 68 + rrow]; gf1 += p[(1 * 16 + jl0 + 1) * 68 + rrow];
        gg0 += p[(2 * 16 + jl0) * 68 + rrow]; gg1 += p[(2 * 16 + jl0 + 1) * 68 + rrow];
        go0 += p[(3 * 16 + jl0) * 68 + rrow]; go1 += p[(3 * 16 + jl0 + 1) * 68 + rrow];
      }
      float i0 = 1.f / (1.f + __expf(-gi0)), i1 = 1.f / (1.f + __expf(-gi1));
      float f0 = 1.f / (1.f + __expf(-gf0)), f1 = 1.f / (1.f + __expf(-gf1));
      float g0 = tanhf(gg0), g1 = tanhf(gg1);
      float o0 = 1.f / (1.f + __expf(-go0)), o1 = 1.f / (1.f + __expf(-go1));
      cst0 = f0 * cst0 + i0 * g0;
      cst1 = f1 * cst1 + i1 * g1;
      float h0v = o0 * tanhf(cst0);
      float h1v = o1 * tanhf(cst1);

      float2 yv; yv.x = h0v; yv.y = h1v;
      *reinterpret_cast<float2*>(out + ((size_t)t * BATCH + row0) * (2 * HDIM)
                                     + (size_t)dir * HDIM + jg0) = yv;

      // publish h for step s+1 (packed 2x bf16, write-through to LLC)
      unsigned hp = (unsigned)f2b(h0v) | ((unsigned)f2b(h1v) << 16);
      u16* hdst;
      if (use_roll)
        hdst = hroll + ((size_t)(s + 1) * 2 + dir) * BATCH * HDIM;
      else
        hdst = hbuf + ((size_t)(s & 1) * 2 + dir) * BATCH * HDIM;
      __hip_atomic_store(reinterpret_cast<unsigned*>(hdst + (size_t)row0 * HDIM + jg0),
                         hp, __ATOMIC_RELAXED, __HIP_MEMORY_SCOPE_AGENT);

      if (s == T_STEPS - 1) {
        size_t hid = (size_t)T_STEPS * BATCH * 2 * HDIM;
        size_t base2 = hid + (size_t)dir * 2 * BATCH * HDIM;
        *reinterpret_cast<float2*>(out + base2 + (size_t)row0 * HDIM + jg0) = yv;
        float2 cv; cv.x = cst0; cv.y = cst1;
        *reinterpret_cast<float2*>(out + base2 + (size_t)BATCH * HDIM
                                       + (size_t)row0 * HDIM + jg0) = cv;
      }
    }

    // ---- release: ack stores at LLC -> all waves done -> post flag ----
    asm volatile("s_waitcnt vmcnt(0)" ::: "memory");
    __syncthreads();
    if (tid == 0)
      __hip_atomic_store(flags + grp * 64 + jt, (unsigned)(s + 1),
                         __ATOMIC_RELAXED, __HIP_MEMORY_SCOPE_AGENT);
  }
}

extern "C" void kernel_launch(void* const* d_in, const int* in_sizes, int n_in,
                              void* d_out, int out_size, void* d_ws, size_t ws_size,
                              hipStream_t stream) {
  const float* x     = (const float*)d_in[0];
  const float* h0f   = (const float*)d_in[1];
  const float* c0f   = (const float*)d_in[2];
  const float* h0r   = (const float*)d_in[3];
  const float* c0r   = (const float*)d_in[4];
  const float* Wih_f = (const float*)d_in[5];
  const float* Whh_f = (const float*)d_in[6];
  const float* bih_f = (const float*)d_in[7];
  const float* bhh_f = (const float*)d_in[8];
  const float* Wih_r = (const float*)d_in[9];
  const float* Whh_r = (const float*)d_in[10];
  const float* bih_r = (const float*)d_in[11];
  const float* bhh_r = (const float*)d_in[12];
  float* out = (float*)d_out;
  char* ws = (char*)d_ws;

  if (ws_size < WS_SMALL) return;
  int use_roll = (ws_size >= WS_BIG) ? 1 : 0;

  u16* xbf        = (u16*)(ws + OFF_XBF);
  u16* Bm         = (u16*)(ws + OFF_BM);
  u16* hbuf       = (u16*)(ws + OFF_HBUF);
  float* bias     = (float*)(ws + OFF_BIAS);
  unsigned* flags = (unsigned*)(ws + OFF_CNT);
  u16* hroll      = (u16*)(ws + OFF_ROLL);

  k_cast_x<<<8192, 256, 0, stream>>>(x, xbf);
  k_build_b<<<128, 256, 0, stream>>>(Whh_f, Wih_f, Whh_r, Wih_r, Bm);
  k_init<<<1024, 256, 0, stream>>>(h0f, h0r, bih_f, bhh_f, bih_r, bhh_r,
                                   hbuf, hroll, use_roll, bias, flags);
  k_lstm<<<256, 512, 0, stream>>>(xbf, Bm, hbuf, hroll, use_roll, bias, flags,
                                  c0f, c0r, out);
}